// Round 8
// baseline (149.629 us; speedup 1.0000x reference)
//
#include <hip/hip_runtime.h>

#define NPOS 32768   // 32 * 32 * 32 positions
#define DDIM 256
#define KCODES 1024

typedef __attribute__((ext_vector_type(8))) short bf16x8;
typedef __attribute__((ext_vector_type(4))) float f32x4;
typedef unsigned long long u64;

// ---- fp32 ops with anti-contraction barriers (replicate numpy rounding) ----
__device__ __forceinline__ float sqr_rn(float x) {
    float r = x * x;
    asm volatile("" : "+v"(r));
    return r;
}
__device__ __forceinline__ float add_rn(float a, float b) {
    float r = a + b;
    asm volatile("" : "+v"(r));
    return r;
}

// fp32 -> bf16 round-to-nearest-even (verbatim from verified kernel)
__device__ __forceinline__ unsigned short f2bf(float x) {
    unsigned u = __float_as_uint(x);
    return (unsigned short)((u + 0x7fffu + ((u >> 16) & 1u)) >> 16);
}

// monotone pack: float score -> order-preserving u32, | code in low bits
__device__ __forceinline__ u64 packm(float s, int code) {
    unsigned b = __float_as_uint(s);
    unsigned mm = ((unsigned)((int)b >> 31)) | 0x80000000u;
    return ((u64)(b ^ mm) << 32) | (unsigned)code;
}

// async global->LDS, 16B per lane (dest = wave-uniform base + lane*16)
__device__ __forceinline__ void gload_lds16(const void* g, void* l) {
    __builtin_amdgcn_global_load_lds(
        (const __attribute__((address_space(1))) void*)g,
        (__attribute__((address_space(3))) void*)l, 16, 0, 0);
}

// ---------------- wprep: wsq + W bf16 tiled (verbatim from verified prep) ----------------
__global__ __launch_bounds__(256) void wprep(const float* __restrict__ W,
                                             float* __restrict__ wsq,
                                             unsigned short* __restrict__ wb16t) {
    const int t   = threadIdx.x;
    const int bid = blockIdx.x;
    const int row = bid * 16 + (t >> 4);
    const int j   = t & 15;
    const float* base = W + row * DDIM + (j & 7) + (j >> 3) * 128;
    float r = sqr_rn(base[0]);
#pragma unroll
    for (int i = 1; i < 16; ++i) r = add_rn(r, sqr_rn(base[i * 8]));
#pragma unroll
    for (int m = 1; m <= 8; m <<= 1) r = add_rn(r, __shfl_xor(r, m));
    if (j == 0) wsq[row] = r;
#pragma unroll
    for (int jj = 0; jj < 2; ++jj) {
        const int u  = t + jj * 256;      // 512 units = 16 rows x 32 k8
        const int n  = bid * 16 + (u >> 5);
        const int k8 = u & 31;
        const float4 f0 = *(const float4*)&W[n * DDIM + k8 * 8];
        const float4 f1 = *(const float4*)&W[n * DDIM + k8 * 8 + 4];
        bf16x8 o;
        o[0] = (short)f2bf(f0.x); o[1] = (short)f2bf(f0.y);
        o[2] = (short)f2bf(f0.z); o[3] = (short)f2bf(f0.w);
        o[4] = (short)f2bf(f1.x); o[5] = (short)f2bf(f1.y);
        o[6] = (short)f2bf(f1.z); o[7] = (short)f2bf(f1.w);
        const int kk = k8 >> 2, kq = k8 & 3;
        *(bf16x8*)&wb16t[(n >> 8) * 65536 + kk * 8192 + kq * 2048 + (n & 255) * 8] = o;
    }
}

// ---------------- fused: m97-style LDS-staged GEMM + top-2 + exact rescore ----------------
// Grid 256 (1 block/CU), 512 threads = 8 waves (4 m-quarters x 2 n-halves).
// BM=128 positions per block. B-panels staged global->LDS via
// global_load_lds width-16, double-buffered per 16KB kk-slice (contiguous in
// wb16t); all 8 waves share the staged slice (halves L2 traffic vs r7 and
// replaces ~300cyc L2 latency on the MFMA operand path with ~120cyc LDS).
// Candidate semantics (exact top-2 per 256-code panel per row) and the
// numpy-bit-exact rescore are unchanged from verified rounds.
#define ZS 260   // floats per Zs row (bank-spread, as verified)
__global__ __launch_bounds__(512)
void vq_fused(const float* __restrict__ z,
              const float* __restrict__ W,
              const float* __restrict__ wsq,
              const unsigned short* __restrict__ wb16t,
              int* __restrict__ out) {
    union Sm {
        unsigned short At[32768];   // 64 KB bf16 A-tile [k8(32)][m(128)][e(8)]
        float          Zs[64 * ZS]; // 66.6 KB fp32 rescore tile (Phase C only)
    };
    __shared__ Sm   sm;
    __shared__ char Bb[2][16384];   // 32 KB B kk-slice double buffer
    __shared__ u64  redP[128 * 4];  // 4 KB: [row][nhalf(2)][2] per-panel scratch
    __shared__ u64  candL[128 * 8]; // 8 KB: [row][panel(4)][2] = 8 candidates

    const int t    = threadIdx.x;
    const int lane = t & 63;
    const int wid  = t >> 6;
    const int bid  = blockIdx.x;
    const int img  = bid >> 3;          // 8 blocks per image
    const int p0   = (bid & 7) * 128;   // first position within image

    // ---- Phase A: z -> bf16 A-tile in LDS (same f2bf/tiling as verified) ----
    {
        const float* zbase = z + img * (DDIM * 1024) + p0;
#pragma unroll
        for (int jj = 0; jj < 8; ++jj) {
            const int u_ = t + jj * 512;     // 4096 units = 128 m x 32 k8
            const int m  = u_ & 127;
            const int k8 = u_ >> 7;
            const float* src = zbase + k8 * 8192 + m;   // d = k8*8+e, stride 1024 floats
            bf16x8 o;
#pragma unroll
            for (int e = 0; e < 8; ++e) o[e] = (short)f2bf(src[e * 1024]);
            *(bf16x8*)&sm.At[k8 * 1024 + m * 8] = o;    // byte addr k8*2048 + m*16
        }
    }

    // ---- prologue: stage B slice for step 0 (panel 0, kk 0) into Bb[0] ----
    {
        const char* gsrc = (const char*)wb16t + wid * 2048 + lane * 16;
        char* ldst = &Bb[0][wid * 2048];
        gload_lds16(gsrc, ldst);
        gload_lds16(gsrc + 1024, ldst + 1024);
    }
    __syncthreads();   // drains Phase A ds_writes + prologue DMA

    // ---- Phase B: 32 steps = 4 panels x 8 kk; 16 MFMA/wave/step ----
    const int ln = lane & 15;
    const int q  = lane >> 4;
    const int mq = wid >> 1;        // m-quarter 0..3
    const int nh = wid & 1;         // n-half 0..1

    float wq[8];
    f32x4 acc[2][8];

#pragma unroll 1
    for (int s = 0; s < 32; ++s) {
        const int panel = s >> 3;
        const int kk    = s & 7;
        const int cur   = s & 1;

        if (kk == 0) {
#pragma unroll
            for (int nf = 0; nf < 8; ++nf)
                wq[nf] = wsq[panel * 256 + nh * 128 + nf * 16 + ln];
#pragma unroll
            for (int a = 0; a < 2; ++a)
#pragma unroll
                for (int b = 0; b < 8; ++b) acc[a][b] = (f32x4)(0.f);
        }

        // stage next kk-slice (contiguous 16 KB in wb16t) into the other buffer
        if (s < 31) {
            const int s1  = s + 1;
            const int off = (s1 >> 3) * 131072 + (s1 & 7) * 16384;
            const char* gsrc = (const char*)wb16t + off + wid * 2048 + lane * 16;
            char* ldst = &Bb[cur ^ 1][wid * 2048];
            gload_lds16(gsrc, ldst);
            gload_lds16(gsrc + 1024, ldst + 1024);
        }

        // fragments from LDS (bit-identical contents to verified global path)
        bf16x8 afr[2], bfr[8];
        {
            const char* ab = (const char*)sm.At + (kk * 4 + q) * 2048 + (mq * 32 + ln) * 16;
            afr[0] = *(const bf16x8*)ab;
            afr[1] = *(const bf16x8*)(ab + 256);
            const char* bb = &Bb[cur][q * 4096 + (nh * 128 + ln) * 16];
#pragma unroll
            for (int nf = 0; nf < 8; ++nf)
                bfr[nf] = *(const bf16x8*)(bb + nf * 256);
        }
#pragma unroll
        for (int nf = 0; nf < 8; ++nf)
#pragma unroll
            for (int mf = 0; mf < 2; ++mf)
                acc[mf][nf] = __builtin_amdgcn_mfma_f32_16x16x32_bf16(
                    afr[mf], bfr[nf], acc[mf][nf], 0, 0, 0);

        if (kk == 7) {
            // epilogue: score = wsq - 2*acc; exact top-2 per (row, 128-col slice)
            const int n0 = panel * 256;
#pragma unroll
            for (int mf = 0; mf < 2; ++mf) {
#pragma unroll
                for (int reg = 0; reg < 4; ++reg) {
                    const int row = mq * 32 + mf * 16 + q * 4 + reg;
                    float s0 = 1e30f, s1 = 1e30f;
                    int   i0 = 0,     i1 = 0;
#pragma unroll
                    for (int nf = 0; nf < 8; ++nf) {
                        const float sc = fmaf(-2.f, acc[mf][nf][reg], wq[nf]);
                        const int   cc = n0 + nh * 128 + nf * 16 + ln;
                        if (sc < s0)      { s1 = s0; i1 = i0; s0 = sc; i0 = cc; }
                        else if (sc < s1) { s1 = sc; i1 = cc; }
                    }
                    u64 c0 = packm(s0, i0), c1 = packm(s1, i1);
#pragma unroll
                    for (int m = 1; m <= 8; m <<= 1) {
                        const u64 o0 = __shfl_xor(c0, m);
                        const u64 o1 = __shfl_xor(c1, m);
                        const u64 hi = (c0 < o0) ? o0 : c0;
                        c0 = (c0 < o0) ? c0 : o0;
                        const u64 lo = (c1 < o1) ? c1 : o1;
                        c1 = (hi < lo) ? hi : lo;
                    }
                    if (ln == 0) {
                        redP[row * 4 + nh * 2]     = c0;
                        redP[row * 4 + nh * 2 + 1] = c1;
                    }
                }
            }
            __syncthreads();
            if (t < 128) {   // merge 2 sorted n-half pairs -> panel top-2
                const u64 a = redP[t * 4],     b = redP[t * 4 + 1];
                const u64 c = redP[t * 4 + 2], d = redP[t * 4 + 3];
                const u64 m1 = (a < c) ? a : c;
                const u64 hi = (a < c) ? c : a;
                const u64 lo = (b < d) ? b : d;
                const u64 m2 = (hi < lo) ? hi : lo;
                candL[t * 8 + panel * 2]     = m1;
                candL[t * 8 + panel * 2 + 1] = m2;
            }
        }
        __syncthreads();   // next slice staged; buf[cur] reads done; redP safe
    }

    // ---- Phase C: exact numpy-bit rescore (verbatim arithmetic), 2 x 64 pos ----
    const float* zimg = z + img * (DDIM * 1024) + p0;
#pragma unroll 1
    for (int ch = 0; ch < 2; ++ch) {
#pragma unroll
        for (int jj = 0; jj < 8; ++jj) {
            const int f4 = t + jj * 512;     // 4096 float4 = 256 d x 16 p4
            const int d = f4 >> 4, p4 = f4 & 15;
            const float4 v = *(const float4*)&zimg[d * 1024 + ch * 64 + p4 * 4];
            sm.Zs[(p4 * 4 + 0) * ZS + d] = v.x;
            sm.Zs[(p4 * 4 + 1) * ZS + d] = v.y;
            sm.Zs[(p4 * 4 + 2) * ZS + d] = v.z;
            sm.Zs[(p4 * 4 + 3) * ZS + d] = v.w;
        }
        __syncthreads();
        {
            const int pl = t >> 3, slot = t & 7;   // 64 pos x 8 slots
            const float* zr = &sm.Zs[pl * ZS];

            // numpy-exact zsq: slot chains + xor butterfly, halves joined last
            float h0 = sqr_rn(zr[slot]);
            float h1 = sqr_rn(zr[128 + slot]);
#pragma unroll
            for (int i = 1; i < 16; ++i) {
                h0 = add_rn(h0, sqr_rn(zr[slot + 8 * i]));
                h1 = add_rn(h1, sqr_rn(zr[128 + slot + 8 * i]));
            }
#pragma unroll
            for (int m = 1; m <= 4; m <<= 1) {
                h0 = add_rn(h0, __shfl_xor(h0, m));
                h1 = add_rn(h1, __shfl_xor(h1, m));
            }
            const float zq = add_rn(h0, h1);

            const int code = (int)(unsigned)(candL[(ch * 64 + pl) * 8 + slot] & 0xffffffffULL);
            const float* wr = W + code * DDIM;
            // sequential fma chain over d ascending — bit-identical to verified path
            float M = 0.f;
#pragma unroll 8
            for (int d4 = 0; d4 < 64; ++d4) {
                const float4 zv = *(const float4*)&zr[d4 * 4];
                const float4 wv = *(const float4*)&wr[d4 * 4];
                M = fmaf(zv.x, wv.x, M);
                M = fmaf(zv.y, wv.y, M);
                M = fmaf(zv.z, wv.z, M);
                M = fmaf(zv.w, wv.w, M);
            }
            const float sc = add_rn(fmaf(-2.f, M, zq), wsq[code]);
            u64 v = ((u64)__float_as_uint(sc) << 32) | (unsigned)code;
#pragma unroll
            for (int m = 1; m <= 4; m <<= 1) {
                const u64 o = __shfl_xor(v, m);
                if (o < v) v = o;
            }
            if (slot == 0) out[img * 1024 + p0 + ch * 64 + pl] = (int)(unsigned)(v & 0xffffffffULL);
        }
        __syncthreads();   // protect Zs reuse for next chunk
    }
}

extern "C" void kernel_launch(void* const* d_in, const int* in_sizes, int n_in,
                              void* d_out, int out_size, void* d_ws, size_t ws_size,
                              hipStream_t stream) {
    const float* z = (const float*)d_in[0];   // [32, 256, 32, 32] NCHW
    const float* W = (const float*)d_in[1];   // [1024, 256]
    int* out = (int*)d_out;                   // [32768] int32 indices

    char* ws = (char*)d_ws;
    float*          wsq   = (float*)ws;                  //   4 KB @ 0
    unsigned short* wb16t = (unsigned short*)(ws + 4096); // 512 KB

    wprep<<<KCODES / 16, 256, 0, stream>>>(W, wsq, wb16t);
    vq_fused<<<NPOS / 128, 512, 0, stream>>>(z, W, wsq, wb16t, out);
}